// Round 16
// baseline (330.842 us; speedup 1.0000x reference)
//
#include <hip/hip_runtime.h>
#include <hip/hip_bf16.h>
#include <math.h>

typedef unsigned short u16;
typedef __attribute__((ext_vector_type(8))) short bhalf8;   // 8 x bf16 (4 VGPR)
typedef __attribute__((ext_vector_type(4))) float f32x4;

#define DEV __device__ __forceinline__

DEV float bf2f(u16 u){ unsigned int i=((unsigned int)u)<<16; float f; __builtin_memcpy(&f,&i,4); return f; }
DEV u16 f2bf(float f){ unsigned int i; __builtin_memcpy(&i,&f,4); i += 0x7FFFu + ((i>>16)&1u); return (u16)(i>>16); }
DEV float gelu_f(float x){ return 0.5f*x*(1.0f+erff(x*0.70710678118654752f)); }
DEV float wredsum(float v){ for(int o=32;o;o>>=1) v+=__shfl_down(v,o); return v; }

// async global->LDS, 16B per lane; LDS dest = wave-uniform base + lane*16
DEV void gload16(const u16* g, u16* l){
  __builtin_amdgcn_global_load_lds(
      (const __attribute__((address_space(1))) void*)g,
      (__attribute__((address_space(3))) void*)l, 16, 0, 0);
}

// scale 1/sqrt(64) folded with log2(e) so flash can use native exp2
#define KAPPA 0.18033688011112042f
// ps storage: row stride 1025 (+1 pad slot/row, pre-zeroed), buffer offset +1.
// bd[i][j] = F[1 + i*1024 + 1023 + j] for ALL j (pad slot realizes the j=i+1 zero).
#define ZSTR 1049664L   // 1025*1024 + 64 (keeps per-z base 128B-aligned)

// ---------------------------------------------------------------------------
// GEMM: C[M,N] = A[M,K] @ Bt[N,K]^T, batched over z=(b,h) via strides.
// T3 2-phase: LDS double-buffer, stage(t+1) before compute(t), counted
// vmcnt((BM+BN)/32) + raw s_barrier. T1 XCD swizzle:
//  - nx==48 (QKV): 2D-chunk per XCD; ny==32: 16by x 12bx (A 2MB + B 1.5MB),
//    ny==16: 8by x 12bx
//  - else: by-interleave (ny in {8,16,32})
// Tiles: 128x64 or 64x64 (64x64: 5 blocks/CU LDS capacity -> TLP overlap).
// EPI bits: 1=+bias0, 2=gelu(out0), 4=out0 bf16 (else f32),
//           8=out1 = acc+bias1 (bf16), 16=out1 = f32 copy of out0,
//           64=QKV routing: gn<1024: C0=qkv + C1=qp; 1024<=gn<2048: C0=qkv(K);
//              gn>=2048: C2=vtb transposed (V^T), qkv V-half skipped
// ---------------------------------------------------------------------------
template<int BM, int BN, int EPI>
__global__ __launch_bounds__(256, 2) void gemm_bt(
    const u16* __restrict__ A, const u16* __restrict__ Bt,
    void* __restrict__ C0, void* __restrict__ C1, void* __restrict__ C2,
    const float* __restrict__ bias0, const float* __restrict__ bias1,
    int M, int N, int K, int lda, int ldb, int ldc, int Hdiv, int bst,
    long sAb, long sAh, long sBb, long sBh, long sCb, long sCh)
{
  constexpr int FM = BM/32, FN = BN/32;
  constexpr int NL = (BM+BN)/32;     // global_load_lds ops per stage
  static_assert(NL==6 || NL==4, "vmcnt literal for this tile not wired");
  __shared__ __align__(16) u16 sA[2][BM][64];
  __shared__ __align__(16) u16 sB[2][BN][64];
  // ---- T1 XCD-aware remap (dispatch order: x fastest; xcd = flat % 8) ----
  const int bflat = blockIdx.y * gridDim.x + blockIdx.x;
  const int bq = bflat >> 3, br = bflat & 7;
  int bx, by;
  if (gridDim.x == 48){              // QKV: 2D chunk per XCD
    if (gridDim.y == 32){            // 64x64 tile: 16by x 12bx per XCD
      by = 16*(br & 1) + (bq & 15);
      bx = 12*(br >> 1) + (bq >> 4);
    } else {                         // 128x64 tile: 8by x 12bx per XCD
      by = 8*(br & 1) + (bq & 7);
      bx = 12*(br >> 1) + (bq >> 3);
    }
  } else {
    const int kb = (gridDim.y==32) ? 2 : (gridDim.y==16) ? 1 : 0;
    by = br + 8*(bq & ((1<<kb)-1));
    bx = bq >> kb;
  }
  const int z  = blockIdx.z;
  const int bb = z / Hdiv, hh = z % Hdiv;
  const u16* Ab = A + (long)bb*sAb + (long)hh*sAh + (long)by*BM*lda;
  const u16* Bb = Bt + (long)bb*sBb + (long)hh*sBh + (long)bx*BN*ldb;
  const long coff = (long)bb*sCb + (long)hh*sCh;
  const int m0 = by*BM, n0 = bx*BN;
  const int tid = threadIdx.x, lane = tid&63, wave = tid>>6;
  const int wm = wave>>1, wn = wave&1;
  const int rl = lane&15, g = lane>>4;
  const int rswz = rl & 7;

  auto stage = [&](int buf, int kt){
    #pragma unroll
    for (int i=0;i<BM/32;i++){
      int idx = i*256 + tid;
      int r = idx>>3, s = (idx&7) ^ (r&7);
      gload16(Ab + (long)r*lda + kt + s*8, &sA[buf][0][0] + (long)(i*256 + wave*64)*8);
    }
    #pragma unroll
    for (int i=0;i<BN/32;i++){
      int idx = i*256 + tid;
      int r = idx>>3, s = (idx&7) ^ (r&7);
      gload16(Bb + (long)r*ldb + kt + s*8, &sB[buf][0][0] + (long)(i*256 + wave*64)*8);
    }
  };

  f32x4 acc[FM][FN] = {};
  const int nt = K >> 6;
  stage(0, 0);
  int cur = 0;
  for (int t=0; t<nt; ++t){
    if (t+1 < nt){
      stage(cur^1, (t+1)<<6);                       // NL more in flight
      if constexpr (NL==6) asm volatile("s_waitcnt vmcnt(6)" ::: "memory");
      else                 asm volatile("s_waitcnt vmcnt(4)" ::: "memory");
    } else {
      asm volatile("s_waitcnt vmcnt(0)" ::: "memory");
    }
    __builtin_amdgcn_s_barrier();                   // buf[cur] ready for all
    #pragma unroll
    for (int ks=0; ks<2; ++ks){
      bhalf8 af[FM], bfr[FN];
      #pragma unroll
      for (int i=0;i<FM;i++){
        int row = wm*(BM/2)+i*16+rl;
        af[i]  = *(const bhalf8*)&sA[cur][row][(((ks*4+g)) ^ rswz)*8];
      }
      #pragma unroll
      for (int j=0;j<FN;j++){
        int row = wn*(BN/2)+j*16+rl;
        bfr[j] = *(const bhalf8*)&sB[cur][row][(((ks*4+g)) ^ rswz)*8];
      }
      #pragma unroll
      for (int i=0;i<FM;i++)
        #pragma unroll
        for (int j=0;j<FN;j++)
          acc[i][j] = __builtin_amdgcn_mfma_f32_16x16x32_bf16(af[i], bfr[j], acc[i][j], 0,0,0);
    }
    __builtin_amdgcn_s_barrier();                   // all reads of buf[cur] done
    cur ^= 1;
  }
  // C/D layout: col = lane&15, row = (lane>>4)*4 + reg
  const int cr = g*4, cc = rl;
  #pragma unroll
  for (int i=0;i<FM;i++){
    const int gm = m0 + wm*(BM/2) + i*16 + cr;
    #pragma unroll
    for (int j=0;j<FN;j++){
      const int gn = n0 + wn*(BN/2) + j*16 + cc;
      const float b0v = (EPI&(1|64)) ? bias0[(long)bb*bst + gn] : 0.0f;
      const float b1v = (EPI&8) ? bias1[gn] : 0.0f;
      f32x4 v = acc[i][j];
      if (EPI&64){
        if (gn >= 2048){
          // V^T: vtb[b][gn-2048][row], rows gm..gm+3 contiguous -> one 8B store
          ushort4 w4 = { f2bf(v[0]+b0v), f2bf(v[1]+b0v), f2bf(v[2]+b0v), f2bf(v[3]+b0v) };
          const long vbase = ((long)(gm>>10))*1048576L + (long)(gn-2048)*1024 + (gm&1023);
          *(ushort4*)((u16*)C2 + vbase) = w4;
        } else {
          #pragma unroll
          for (int jj=0;jj<4;jj++){
            ((u16*)C0)[(long)(gm+jj)*ldc + gn] = f2bf(v[jj] + b0v);
            if (gn < 1024)
              ((u16*)C1)[(long)(gm+jj)*1024 + gn] = f2bf(v[jj] + bias1[gn]);
          }
        }
        continue;
      }
      #pragma unroll
      for (int jj=0;jj<4;jj++){
        const long cidx = coff + (long)(gm+jj)*ldc + gn;
        float o0 = v[jj] + b0v;
        if (EPI&2)  o0 = gelu_f(o0);
        if (EPI&4)  ((u16*)C0)[cidx] = f2bf(o0);
        else        ((float*)C0)[cidx] = o0;
        if (EPI&8)  ((u16*)C1)[cidx] = f2bf(v[jj] + b1v);
        if (EPI&16) ((float*)C1)[cidx] = o0;
      }
    }
  }
}

template<int BM, int BN, int EPI>
static void launch_gemm(hipStream_t s, int M,int N,int K,
    const u16* A,int lda,long sAb,long sAh,
    const u16* Bt,int ldb,long sBb,long sBh,
    void* C0, void* C1, void* C2, int ldc, long sCb, long sCh,
    const float* b0, const float* b1, int bst, int NB, int HD)
{
  gemm_bt<BM,BN,EPI><<<dim3(N/BN, M/BM, NB), dim3(256), 0, s>>>(
      A,Bt,C0,C1,C2,b0,b1,M,N,K,lda,ldb,ldc,HD,bst,sAb,sAh,sBb,sBh,sCb,sCh);
}

// ---------------------------------------------------------------------------
// Flash attention v11 (frozen): z-grouped XCD swizzle, LDS-staged K/V with
// T14 reg-prefetch, swapped QK^T, bd stride-1025 identity (depth-2 prefetch),
// per-lane partial l reduced in epilogue, T5 setprio, T13 defer-max.
// ---------------------------------------------------------------------------
__global__ __launch_bounds__(256) void flash_attn(
    const u16* __restrict__ qkv,  // [2048][3072]: Q(kappa,bias) | K | (unused)
    const u16* __restrict__ vtb,  // [b][1024 dfull][1024 i]  (V^T per batch)
    const u16* __restrict__ bdf,  // stride-1025 ps, +1 offset, pads zeroed
    u16* __restrict__ ab)         // [2048][1024]
{
  const int flat = blockIdx.y * gridDim.x + blockIdx.x;
  const int z  = 4*(flat & 7) + ((flat >> 3) & 3);
  const int i0 = (flat >> 5) * 64;
  const int b = z >> 4, h = z & 15;
  const int tid = threadIdx.x, lane = tid & 63, wave = tid >> 6;
  const int rl = lane & 15, g = lane >> 4;
  const int ig = i0 + wave*16 + rl;          // this lane's i (col of S^T)

  __shared__ u16 kt[128][68];                // [j][d]  stride 34 dw -> 2-way
  __shared__ u16 vt[64][132];                // [d][j]
  __shared__ u16 pw[4][16][132];             // per-wave P: [i][j]

  const u16* qrow = qkv + ((long)(b*1024 + ig))*3072 + h*64;
  const bhalf8 qf0 = *(const bhalf8*)(qrow + g*8);
  const bhalf8 qf1 = *(const bhalf8*)(qrow + 32 + g*8);
  const u16* bdbase = bdf + (long)z*ZSTR + 1 + ((long)ig<<10) + 1023 + g*4;

  bhalf8 kreg[2][2], vreg[2][2];
  ushort4 bdreg[3][8];

  auto issueKV = [&](int jt){
    #pragma unroll
    for (int w = 0; w < 2; ++w){
      int r = (tid>>2) + w*64, c = tid&3;
      const u16* sk = qkv + ((long)(b*1024 + jt*128 + r))*3072 + 1024 + h*64 + c*16;
      kreg[w][0] = *(const bhalf8*)(sk);
      kreg[w][1] = *(const bhalf8*)(sk + 8);
      int d = (tid>>3) + w*32, c2 = tid&7;
      const u16* sv = vtb + (long)b*1048576L + ((long)(h*64 + d))*1024 + jt*128 + c2*16;
      vreg[w][0] = *(const bhalf8*)(sv);
      vreg[w][1] = *(const bhalf8*)(sv + 8);
    }
  };

  issueKV(0);
  // prefill bd for tiles 0 and 1 (depth-2 prefetch)
  #pragma unroll
  for (int pt = 0; pt < 2; ++pt){
    const u16* p = bdbase + pt*128;
    #pragma unroll
    for (int jf = 0; jf < 8; ++jf) bdreg[pt][jf] = *(const ushort4*)(p + jf*16);
  }

  f32x4 o[4] = {};
  float m = -INFINITY, l = 0.f;   // l is PER-LANE PARTIAL (reduced in epilogue)

  #pragma unroll
  for (int jt = 0; jt < 8; ++jt){
    // ---- write prefetched K/V regs -> LDS ----
    __syncthreads();
    #pragma unroll
    for (int w = 0; w < 2; ++w){
      int r = (tid>>2) + w*64, c = tid&3;
      *(bhalf8*)&kt[r][c*16]     = kreg[w][0];
      *(bhalf8*)&kt[r][c*16 + 8] = kreg[w][1];
      int d = (tid>>3) + w*32, c2 = tid&7;
      *(bhalf8*)&vt[d][c2*16]     = vreg[w][0];
      *(bhalf8*)&vt[d][c2*16 + 8] = vreg[w][1];
    }
    __syncthreads();

    // ---- issue next tiles' loads; latency hides under this tile's compute ----
    if (jt < 7) issueKV(jt+1);
    if (jt < 6){
      const u16* p = bdbase + (jt+2)*128;
      #pragma unroll
      for (int jf = 0; jf < 8; ++jf) bdreg[(jt+2)%3][jf] = *(const ushort4*)(p + jf*16);
    }

    // ---- S^T = K . Q^T  (+ bd from regs) ----
    f32x4 s[8];
    __builtin_amdgcn_s_setprio(1);
    #pragma unroll
    for (int jf = 0; jf < 8; ++jf){
      bhalf8 a0 = *(const bhalf8*)&kt[jf*16 + rl][g*8];
      bhalf8 a1 = *(const bhalf8*)&kt[jf*16 + rl][32 + g*8];
      f32x4 acc = {};
      acc = __builtin_amdgcn_mfma_f32_16x16x32_bf16(a0, qf0, acc, 0,0,0);
      acc = __builtin_amdgcn_mfma_f32_16x16x32_bf16(a1, qf1, acc, 0,0,0);
      ushort4 bdv = bdreg[jt%3][jf];
      acc[0] += bf2f(bdv.x); acc[1] += bf2f(bdv.y);
      acc[2] += bf2f(bdv.z); acc[3] += bf2f(bdv.w);
      s[jf] = acc;
    }
    __builtin_amdgcn_s_setprio(0);

    // ---- online softmax; T13 defer-max (THR=11.5 in log2 units) ----
    float mt = s[0][0];
    #pragma unroll
    for (int jf = 0; jf < 8; ++jf)
      #pragma unroll
      for (int r2 = 0; r2 < 4; ++r2) mt = fmaxf(mt, s[jf][r2]);
    mt = fmaxf(mt, __shfl_xor(mt, 16));
    mt = fmaxf(mt, __shfl_xor(mt, 32));
    if (__any(mt > m + 11.5f)){
      const float mnew = fmaxf(m, mt);
      const float alpha = exp2f(m - mnew);   // first tile: exp2(-inf)=0
      l *= alpha;                            // row-uniform alpha: partials stay consistent
      #pragma unroll
      for (int df = 0; df < 4; ++df) o[df] *= alpha;
      m = mnew;
    }
    #pragma unroll
    for (int jf = 0; jf < 8; ++jf)
      #pragma unroll
      for (int r2 = 0; r2 < 4; ++r2){
        float p = exp2f(s[jf][r2] - m);
        l += p; s[jf][r2] = p;
      }

    // ---- P -> LDS (bf16, per-wave region; same-wave, no barrier needed) ----
    #pragma unroll
    for (int jf = 0; jf < 8; ++jf){
      uint2 pk;
      pk.x = (unsigned)f2bf(s[jf][0]) | ((unsigned)f2bf(s[jf][1])<<16);
      pk.y = (unsigned)f2bf(s[jf][2]) | ((unsigned)f2bf(s[jf][3])<<16);
      *(uint2*)&pw[wave][rl][jf*16 + g*4] = pk;
    }

    // ---- O^T += V^T . P^T ----
    __builtin_amdgcn_s_setprio(1);
    #pragma unroll
    for (int df = 0; df < 4; ++df)
      #pragma unroll
      for (int kf = 0; kf < 4; ++kf){
        bhalf8 a  = *(const bhalf8*)&vt[df*16 + rl][kf*32 + g*8];
        bhalf8 bf = *(const bhalf8*)&pw[wave][rl][kf*32 + g*8];
        o[df] = __builtin_amdgcn_mfma_f32_16x16x32_bf16(a, bf, o[df], 0,0,0);
      }
    __builtin_amdgcn_s_setprio(0);
  }

  // ---- epilogue: single cross-lane l reduction, then normalize ----
  l += __shfl_xor(l, 16);
  l += __shfl_xor(l, 32);
  const float rlv = 1.0f / l;
  u16* orow = ab + ((long)(b*1024 + ig))*1024 + h*64;
  #pragma unroll
  for (int df = 0; df < 4; ++df){
    ushort4 w4;
    w4.x = f2bf(o[df][0]*rlv); w4.y = f2bf(o[df][1]*rlv);
    w4.z = f2bf(o[df][2]*rlv); w4.w = f2bf(o[df][3]*rlv);
    *(ushort4*)(orow + df*16 + g*4) = w4;
  }
}

// ---------------------------------------------------------------------------
// LayerNorm: out = gamma * (x1+x2 - mean)/sqrt(var+1e-12) + beta, per row(1024)
// ---------------------------------------------------------------------------
__global__ __launch_bounds__(256) void ln_kernel(
    const float* __restrict__ xa, const float* __restrict__ xb2,
    const float* __restrict__ gamma, const float* __restrict__ beta,
    u16* __restrict__ ob, float* __restrict__ of)
{
  const long row = blockIdx.x;
  const int tid = threadIdx.x;
  const float4 a4 = ((const float4*)(xa  + row*1024))[tid];
  const float4 b4 = ((const float4*)(xb2 + row*1024))[tid];
  float v[4] = {a4.x+b4.x, a4.y+b4.y, a4.z+b4.z, a4.w+b4.w};
  float s = v[0]+v[1]+v[2]+v[3];
  __shared__ float red[4];
  s = wredsum(s);
  const int lane = tid&63, w = tid>>6;
  if (!lane) red[w] = s;
  __syncthreads();
  const float mean = (red[0]+red[1]+red[2]+red[3]) * (1.0f/1024.0f);
  float q = 0.f;
  #pragma unroll
  for (int k=0;k<4;k++){ float d = v[k]-mean; q += d*d; }
  __syncthreads();
  q = wredsum(q);
  if (!lane) red[w] = q;
  __syncthreads();
  const float var = (red[0]+red[1]+red[2]+red[3]) * (1.0f/1024.0f);
  const float rstd = rsqrtf(var + 1e-12f);
  const float4 g4 = ((const float4*)gamma)[tid];
  const float4 be4 = ((const float4*)beta)[tid];
  float oo[4];
  oo[0] = g4.x*(v[0]-mean)*rstd + be4.x;
  oo[1] = g4.y*(v[1]-mean)*rstd + be4.y;
  oo[2] = g4.z*(v[2]-mean)*rstd + be4.z;
  oo[3] = g4.w*(v[3]-mean)*rstd + be4.w;
  ushort4 ob4 = { f2bf(oo[0]), f2bf(oo[1]), f2bf(oo[2]), f2bf(oo[3]) };
  *(ushort4*)(ob + row*1024 + tid*4) = ob4;
  float4 of4 = { oo[0], oo[1], oo[2], oo[3] };
  ((float4*)(of + row*1024))[tid] = of4;
}

// ---------------------------------------------------------------------------
// Weight prep: batched f32->bf16 transposes with scale.
// ---------------------------------------------------------------------------
struct TJobs {
  const float* src[16];
  u16* dst[16];
  int R[16], C[16], nb[16];
  float sc[16];
};

__global__ __launch_bounds__(256) void wprep(TJobs J)
{
  const int j = blockIdx.y;
  const int R = J.R[j], C = J.C[j];
  const float scl = J.sc[j];
  const int tR = R>>5, tC = C>>5;
  const int ntiles = tR*tC*J.nb[j];
  const int t = blockIdx.x;
  if (t >= ntiles) return;
  const int b = t/(tR*tC); const int t2 = t%(tR*tC);
  const int tr = t2/tC, tc = t2%tC;
  const float* src = J.src[j] + (long)b*R*C;
  u16* dst = J.dst[j] + (long)b*R*C;
  __shared__ float tl[32][33];
  const int tx = threadIdx.x & 31, ty = threadIdx.x >> 5;
  #pragma unroll
  for (int k=0;k<4;k++){ int r = ty + k*8; tl[r][tx] = src[(long)(tr*32+r)*C + tc*32 + tx]; }
  __syncthreads();
  #pragma unroll
  for (int k=0;k<4;k++){ int r = ty + k*8;
    dst[(long)(tc*32 + r)*R + tr*32 + tx] = f2bf(tl[tx][r]*scl); }
}

// ---------------------------------------------------------------------------
// misc: x,pos -> bf16; bqkv [l][3072] (Q kappa-scaled | K | V) + bqp [l][1024];
// ps pad-slot zero
// ---------------------------------------------------------------------------
__global__ __launch_bounds__(256) void misc_prep(
    const float* __restrict__ x, const float* __restrict__ pos,
    const float* __restrict__ bq, const float* __restrict__ cb, const float* __restrict__ pbv,
    const float* __restrict__ bk, const float* __restrict__ bv,
    u16* __restrict__ xb, u16* __restrict__ posb,
    float* __restrict__ bqkv, float* __restrict__ bqp,
    u16* __restrict__ bd)
{
  const int n1 = 2048*512, n2 = 1024*1024, n3 = 8192;
  int idx = blockIdx.x*256 + threadIdx.x;
  if (idx < n1) { xb[idx] = f2bf(x[idx]); return; }
  idx -= n1;
  if (idx < n2) { posb[idx] = f2bf(pos[idx]); return; }
  idx -= n2;
  if (idx < n3) {
    int l = idx >> 12; int r = idx & 4095;
    if (r < 3072){
      float val;
      if (r < 1024)       val = (bq[l*1024+r] + cb[l*1024+r]) * KAPPA;
      else if (r < 2048)  val = bk[l*1024 + r-1024];
      else                val = bv[l*1024 + r-2048];
      bqkv[l*3072+r] = val;
    } else {
      int n = r - 3072;
      bqp[l*1024+n] = (bq[l*1024+n] + pbv[l*1024+n]) * KAPPA;
    }
    return;
  }
  idx -= n3;
  if (idx < 32*1024) {
    int z = idx >> 10, i = idx & 1023;
    // zero pad slot of each ps row: realizes bd[i][i+1] = 0
    bd[(long)z*ZSTR + 1 + (long)i*1025 + 1024] = 0;
  }
}

// ---------------------------------------------------------------------------
extern "C" void kernel_launch(void* const* d_in, const int* in_sizes, int n_in,
                              void* d_out, int out_size, void* d_ws, size_t ws_size,
                              hipStream_t stream)
{
  (void)in_sizes; (void)n_in; (void)out_size; (void)ws_size;
  const float* x    = (const float*)d_in[0];
  const float* pos  = (const float*)d_in[1];
  const float* Wh1  = (const float*)d_in[2];
  const float* bh1  = (const float*)d_in[3];
  const float* Wh2  = (const float*)d_in[4];
  const float* bh2  = (const float*)d_in[5];
  const float* Wq   = (const float*)d_in[6];
  const float* bq   = (const float*)d_in[7];
  const float* Wk   = (const float*)d_in[8];
  const float* bk   = (const float*)d_in[9];
  const float* Wv   = (const float*)d_in[10];
  const float* bv   = (const float*)d_in[11];
  const float* Wp   = (const float*)d_in[12];
  const float* bp   = (const float*)d_in[13];
  const float* cbias= (const float*)d_in[14];
  const float* pbias= (const float*)d_in[15];
  const float* Wo   = (const float*)d_in[16];
  const float* bo   = (const float*)d_in[17];
  const float* Wf1  = (const float*)d_in[18];
  const float* bf1  = (const float*)d_in[19];
  const float* Wf2  = (const float*)d_in[20];
  const float* bf2  = (const float*)d_in[21];
  const float* lnw  = (const float*)d_in[22];
  const float* lnb  = (const float*)d_in[23];

  const long EL = 1048576L;
  char* ws = (char*)d_ws;
  size_t off = 0;
  auto alloc = [&](size_t bytes)->char* {
    char* p = ws + off; off += (bytes + 255) & ~(size_t)255; return p;
  };
  u16* xb    = (u16*)alloc(2048L*512*2);
  u16* posb  = (u16*)alloc(EL*2);
  u16* Wh1t  = (u16*)alloc(512L*1024*2);
  u16* Wh2t  = (u16*)alloc(EL*2);
  u16* Wqkvt = (u16*)alloc(6*EL*2);     // per layer [3072][1024]: Wq^T|Wk^T|Wv^T
  u16* Wpt   = (u16*)alloc(2*EL*2);
  u16* Wot   = (u16*)alloc(2*EL*2);
  u16* Wf1t  = (u16*)alloc(2*EL*2);
  u16* Wf2t  = (u16*)alloc(2*EL*2);
  float* bqkv= (float*)alloc(2*3072*4);
  float* bqp = (float*)alloc(2*1024*4);
  u16* t1    = (u16*)alloc(2048L*1024*2);
  u16* hb    = (u16*)alloc(2048L*1024*2);
  float* hf  = (float*)alloc(2048L*1024*4);
  u16* qkvb  = (u16*)alloc(2048L*3072*2);  // [2048][3072] Q|K|(V unused)
  u16* qp    = (u16*)alloc(2048L*1024*2);
  u16* vtb   = (u16*)alloc(2048L*1024*2);
  u16* pb    = (u16*)alloc(2*EL*2);        // both layers' pos projections
  u16* bd    = (u16*)alloc(32L*ZSTR*2);    // stride-1025 ps (pre-shifted bd view)
  u16* ab    = (u16*)alloc(2048L*1024*2);
  float* aof = (float*)alloc(2048L*1024*4);
  u16* h1b   = (u16*)alloc(2048L*1024*2);
  float* h1f = (float*)alloc(2048L*1024*4);
  u16* f1b   = (u16*)alloc(2048L*1024*2);
  float* f2f = (float*)alloc(2048L*1024*4);

  // ---- setup ----
  misc_prep<<<dim3((2048*512 + 1024*1024 + 8192 + 32*1024 + 255)/256),
              dim3(256), 0, stream>>>(
      x, pos, bq, cbias, pbias, bk, bv, xb, posb, bqkv, bqp, bd);

  TJobs J; int ji = 0;
  auto addjob = [&](const float* s, u16* d, int R, int C, int nb, float sc){
    J.src[ji]=s; J.dst[ji]=d; J.R[ji]=R; J.C[ji]=C; J.nb[ji]=nb; J.sc[ji]=sc; ji++;
  };
  addjob(Wh1, Wh1t, 512, 1024, 1, 1.f);
  addjob(Wh2, Wh2t, 1024, 1024, 1, 1.f);
  for (int l=0;l<2;l++) addjob(Wq + l*EL, Wqkvt + l*3*EL,        1024, 64, 16, KAPPA);
  for (int l=0;l<2;l++) addjob(Wk + l*EL, Wqkvt + l*3*EL + EL,   1024, 64, 16, 1.f);
  for (int l=0;l<2;l++) addjob(Wv + l*EL, Wqkvt + l*3*EL + 2*EL, 1024, 64, 16, 1.f);
  for (int l=0;l<2;l++) addjob(Wp + l*EL, Wpt + l*EL, 1024, 64, 16, 1.f);
  for (int l=0;l<2;l++) addjob(Wo + l*EL, Wot + l*EL, 1024, 1024, 1, 1.f);
  for (int l=0;l<2;l++) addjob(Wf1 + l*EL, Wf1t + l*EL, 1024, 1024, 1, 1.f);
  for (int l=0;l<2;l++) addjob(Wf2 + l*EL, Wf2t + l*EL, 1024, 1024, 1, 1.f);
  wprep<<<dim3(1024, 16), dim3(256), 0, stream>>>(J);

  // ---- to_hidden MLP (64x64 tiles: TLP overlap) ----
  launch_gemm<64,64,7>(stream, 2048,1024,512,  xb,512,0,0,  Wh1t,512,0,0,
                 t1,nullptr,nullptr,1024,0,0,  bh1,nullptr, 0, 1,1);
  launch_gemm<64,64,21>(stream, 2048,1024,1024, t1,1024,0,0, Wh2t,1024,0,0,
                 hb,hf,nullptr,1024,0,0,  bh2,nullptr, 0, 1,1);

  // ---- both layers' pos projections in one batched launch (z = layer) ----
  launch_gemm<64,64,5>(stream, 1024,1024,1024, posb,1024, 0,0, Wpt,1024, EL,0,
                 pb,nullptr,nullptr,1024, EL,0,  bp,nullptr, 1024, 2,1);

  for (int l=0; l<2; l++){
    const u16 *Wqkvt_l = Wqkvt + l*3*EL, *Wot_l = Wot + l*EL,
              *Wf1t_l = Wf1t + l*EL, *Wf2t_l = Wf2t + l*EL;
    // fused QKV: N=3072, 64x64 tile -> 1536 blocks (5 blocks/CU LDS capacity);
    // Q-seg dual-out, V-seg -> vtb^T
    launch_gemm<64,64,64>(stream, 2048,3072,1024, hb,1024,0,0, Wqkvt_l,1024,0,0,
                    qkvb,qp,vtb,3072,0,0,  bqkv + l*3072, bqp + l*1024, 0, 1,1);
    // ps = qp@p^T, stored stride-1025 (+1 offset) => pre-shifted bd view
    launch_gemm<128,64,4>(stream, 1024,1024,64,  qp,1024, EL,64,  pb + l*EL,1024, 0,64,
                    bd+1,nullptr,nullptr,1025, 16L*ZSTR, ZSTR,  nullptr,nullptr, 0, 32,16);
    // fused attention (v11, frozen)
    flash_attn<<<dim3(16,32), dim3(256), 0, stream>>>(qkvb, vtb, bd, ab);
    // output proj
    launch_gemm<64,64,1>(stream, 2048,1024,1024, ab,1024,0,0, Wot_l,1024,0,0,
                    aof,nullptr,nullptr,1024,0,0,  bo + l*1024, nullptr, 0, 1,1);
    // h1 = LN(a + h)
    ln_kernel<<<dim3(2048), dim3(256), 0, stream>>>(aof, hf, lnw + l*1024, lnb + l*1024, h1b, h1f);
    // FFN
    launch_gemm<64,64,7>(stream, 2048,1024,1024, h1b,1024,0,0, Wf1t_l,1024,0,0,
                    f1b,nullptr,nullptr,1024,0,0,  bf1 + l*1024, nullptr, 0, 1,1);
    launch_gemm<64,64,1>(stream, 2048,1024,1024, f1b,1024,0,0, Wf2t_l,1024,0,0,
                    f2f,nullptr,nullptr,1024,0,0,  bf2 + l*1024, nullptr, 0, 1,1);
    // h = LN(h1 + f)
    float* outf = (l==1) ? (float*)d_out : hf;
    ln_kernel<<<dim3(2048), dim3(256), 0, stream>>>(f2f, h1f, lnw + l*1024, lnb + l*1024, hb, outf);
  }
}

// Round 17
// 316.716 us; speedup vs baseline: 1.0446x; 1.0446x over previous
//
#include <hip/hip_runtime.h>
#include <hip/hip_bf16.h>
#include <math.h>

typedef unsigned short u16;
typedef __attribute__((ext_vector_type(8))) short bhalf8;   // 8 x bf16 (4 VGPR)
typedef __attribute__((ext_vector_type(4))) float f32x4;

#define DEV __device__ __forceinline__

DEV float bf2f(u16 u){ unsigned int i=((unsigned int)u)<<16; float f; __builtin_memcpy(&f,&i,4); return f; }
DEV u16 f2bf(float f){ unsigned int i; __builtin_memcpy(&i,&f,4); i += 0x7FFFu + ((i>>16)&1u); return (u16)(i>>16); }
DEV float gelu_f(float x){ return 0.5f*x*(1.0f+erff(x*0.70710678118654752f)); }
DEV float wredsum(float v){ for(int o=32;o;o>>=1) v+=__shfl_down(v,o); return v; }

// async global->LDS, 16B per lane; LDS dest = wave-uniform base + lane*16
DEV void gload16(const u16* g, u16* l){
  __builtin_amdgcn_global_load_lds(
      (const __attribute__((address_space(1))) void*)g,
      (__attribute__((address_space(3))) void*)l, 16, 0, 0);
}

// scale 1/sqrt(64) folded with log2(e) so flash can use native exp2
#define KAPPA 0.18033688011112042f
// ps storage: row stride 1025 (+1 pad slot/row, pre-zeroed), buffer offset +1.
// bd[i][j] = F[1 + i*1024 + 1023 + j] for ALL j (pad slot realizes the j=i+1 zero).
#define ZSTR 1049664L   // 1025*1024 + 64 (keeps per-z base 128B-aligned)

// ---------------------------------------------------------------------------
// GEMM: C[M,N] = A[M,K] @ Bt[N,K]^T, batched over z=(b,h) via strides.
// T3 2-phase: LDS double-buffer, stage(t+1) before compute(t), counted
// vmcnt((BM+BN)/32) + raw s_barrier. T1 XCD swizzle:
//  - nx==48 (QKV, 128x64 only): 2D-chunk per XCD (8by x 12bx)
//  - else: by-interleave (ny in {8,16,32})
// Tiles: 128x64 (high-reuse large-N) or 64x64 (N=1024 class: TLP overlap).
// Tile choice is operand-footprint-dependent: smaller BM doubles B traffic
// (round-16 lesson: QKV at 64x64 regressed +12us).
// EPI bits: 1=+bias0, 2=gelu(out0), 4=out0 bf16 (else f32),
//           8=out1 = acc+bias1 (bf16), 16=out1 = f32 copy of out0,
//           64=QKV routing: gn<1024: C0=qkv + C1=qp; 1024<=gn<2048: C0=qkv(K);
//              gn>=2048: C2=vtb transposed (V^T), qkv V-half skipped
// ---------------------------------------------------------------------------
template<int BM, int BN, int EPI>
__global__ __launch_bounds__(256, 2) void gemm_bt(
    const u16* __restrict__ A, const u16* __restrict__ Bt,
    void* __restrict__ C0, void* __restrict__ C1, void* __restrict__ C2,
    const float* __restrict__ bias0, const float* __restrict__ bias1,
    int M, int N, int K, int lda, int ldb, int ldc, int Hdiv, int bst,
    long sAb, long sAh, long sBb, long sBh, long sCb, long sCh)
{
  constexpr int FM = BM/32, FN = BN/32;
  constexpr int NL = (BM+BN)/32;     // global_load_lds ops per stage
  static_assert(NL==6 || NL==4, "vmcnt literal for this tile not wired");
  __shared__ __align__(16) u16 sA[2][BM][64];
  __shared__ __align__(16) u16 sB[2][BN][64];
  // ---- T1 XCD-aware remap (dispatch order: x fastest; xcd = flat % 8) ----
  const int bflat = blockIdx.y * gridDim.x + blockIdx.x;
  const int bq = bflat >> 3, br = bflat & 7;
  int bx, by;
  if (gridDim.x == 48){              // QKV 128x64: 8by x 12bx chunk per XCD
    by = 8*(br & 1) + (bq & 7);
    bx = 12*(br >> 1) + (bq >> 3);
  } else {
    const int kb = (gridDim.y==32) ? 2 : (gridDim.y==16) ? 1 : 0;
    by = br + 8*(bq & ((1<<kb)-1));
    bx = bq >> kb;
  }
  const int z  = blockIdx.z;
  const int bb = z / Hdiv, hh = z % Hdiv;
  const u16* Ab = A + (long)bb*sAb + (long)hh*sAh + (long)by*BM*lda;
  const u16* Bb = Bt + (long)bb*sBb + (long)hh*sBh + (long)bx*BN*ldb;
  const long coff = (long)bb*sCb + (long)hh*sCh;
  const int m0 = by*BM, n0 = bx*BN;
  const int tid = threadIdx.x, lane = tid&63, wave = tid>>6;
  const int wm = wave>>1, wn = wave&1;
  const int rl = lane&15, g = lane>>4;
  const int rswz = rl & 7;

  auto stage = [&](int buf, int kt){
    #pragma unroll
    for (int i=0;i<BM/32;i++){
      int idx = i*256 + tid;
      int r = idx>>3, s = (idx&7) ^ (r&7);
      gload16(Ab + (long)r*lda + kt + s*8, &sA[buf][0][0] + (long)(i*256 + wave*64)*8);
    }
    #pragma unroll
    for (int i=0;i<BN/32;i++){
      int idx = i*256 + tid;
      int r = idx>>3, s = (idx&7) ^ (r&7);
      gload16(Bb + (long)r*ldb + kt + s*8, &sB[buf][0][0] + (long)(i*256 + wave*64)*8);
    }
  };

  f32x4 acc[FM][FN] = {};
  const int nt = K >> 6;
  stage(0, 0);
  int cur = 0;
  for (int t=0; t<nt; ++t){
    if (t+1 < nt){
      stage(cur^1, (t+1)<<6);                       // NL more in flight
      if constexpr (NL==6) asm volatile("s_waitcnt vmcnt(6)" ::: "memory");
      else                 asm volatile("s_waitcnt vmcnt(4)" ::: "memory");
    } else {
      asm volatile("s_waitcnt vmcnt(0)" ::: "memory");
    }
    __builtin_amdgcn_s_barrier();                   // buf[cur] ready for all
    #pragma unroll
    for (int ks=0; ks<2; ++ks){
      bhalf8 af[FM], bfr[FN];
      #pragma unroll
      for (int i=0;i<FM;i++){
        int row = wm*(BM/2)+i*16+rl;
        af[i]  = *(const bhalf8*)&sA[cur][row][(((ks*4+g)) ^ rswz)*8];
      }
      #pragma unroll
      for (int j=0;j<FN;j++){
        int row = wn*(BN/2)+j*16+rl;
        bfr[j] = *(const bhalf8*)&sB[cur][row][(((ks*4+g)) ^ rswz)*8];
      }
      #pragma unroll
      for (int i=0;i<FM;i++)
        #pragma unroll
        for (int j=0;j<FN;j++)
          acc[i][j] = __builtin_amdgcn_mfma_f32_16x16x32_bf16(af[i], bfr[j], acc[i][j], 0,0,0);
    }
    __builtin_amdgcn_s_barrier();                   // all reads of buf[cur] done
    cur ^= 1;
  }
  // C/D layout: col = lane&15, row = (lane>>4)*4 + reg
  const int cr = g*4, cc = rl;
  #pragma unroll
  for (int i=0;i<FM;i++){
    const int gm = m0 + wm*(BM/2) + i*16 + cr;
    #pragma unroll
    for (int j=0;j<FN;j++){
      const int gn = n0 + wn*(BN/2) + j*16 + cc;
      const float b0v = (EPI&(1|64)) ? bias0[(long)bb*bst + gn] : 0.0f;
      const float b1v = (EPI&8) ? bias1[gn] : 0.0f;
      f32x4 v = acc[i][j];
      if (EPI&64){
        if (gn >= 2048){
          // V^T: vtb[b][gn-2048][row], rows gm..gm+3 contiguous -> one 8B store
          ushort4 w4 = { f2bf(v[0]+b0v), f2bf(v[1]+b0v), f2bf(v[2]+b0v), f2bf(v[3]+b0v) };
          const long vbase = ((long)(gm>>10))*1048576L + (long)(gn-2048)*1024 + (gm&1023);
          *(ushort4*)((u16*)C2 + vbase) = w4;
        } else {
          #pragma unroll
          for (int jj=0;jj<4;jj++){
            ((u16*)C0)[(long)(gm+jj)*ldc + gn] = f2bf(v[jj] + b0v);
            if (gn < 1024)
              ((u16*)C1)[(long)(gm+jj)*1024 + gn] = f2bf(v[jj] + bias1[gn]);
          }
        }
        continue;
      }
      #pragma unroll
      for (int jj=0;jj<4;jj++){
        const long cidx = coff + (long)(gm+jj)*ldc + gn;
        float o0 = v[jj] + b0v;
        if (EPI&2)  o0 = gelu_f(o0);
        if (EPI&4)  ((u16*)C0)[cidx] = f2bf(o0);
        else        ((float*)C0)[cidx] = o0;
        if (EPI&8)  ((u16*)C1)[cidx] = f2bf(v[jj] + b1v);
        if (EPI&16) ((float*)C1)[cidx] = o0;
      }
    }
  }
}

template<int BM, int BN, int EPI>
static void launch_gemm(hipStream_t s, int M,int N,int K,
    const u16* A,int lda,long sAb,long sAh,
    const u16* Bt,int ldb,long sBb,long sBh,
    void* C0, void* C1, void* C2, int ldc, long sCb, long sCh,
    const float* b0, const float* b1, int bst, int NB, int HD)
{
  gemm_bt<BM,BN,EPI><<<dim3(N/BN, M/BM, NB), dim3(256), 0, s>>>(
      A,Bt,C0,C1,C2,b0,b1,M,N,K,lda,ldb,ldc,HD,bst,sAb,sAh,sBb,sBh,sCb,sCh);
}

// ---------------------------------------------------------------------------
// Flash attention v11 (frozen): z-grouped XCD swizzle, LDS-staged K/V with
// T14 reg-prefetch, swapped QK^T, bd stride-1025 identity (depth-2 prefetch),
// per-lane partial l reduced in epilogue, T5 setprio, T13 defer-max.
// ---------------------------------------------------------------------------
__global__ __launch_bounds__(256) void flash_attn(
    const u16* __restrict__ qkv,  // [2048][3072]: Q(kappa,bias) | K | (unused)
    const u16* __restrict__ vtb,  // [b][1024 dfull][1024 i]  (V^T per batch)
    const u16* __restrict__ bdf,  // stride-1025 ps, +1 offset, pads zeroed
    u16* __restrict__ ab)         // [2048][1024]
{
  const int flat = blockIdx.y * gridDim.x + blockIdx.x;
  const int z  = 4*(flat & 7) + ((flat >> 3) & 3);
  const int i0 = (flat >> 5) * 64;
  const int b = z >> 4, h = z & 15;
  const int tid = threadIdx.x, lane = tid & 63, wave = tid >> 6;
  const int rl = lane & 15, g = lane >> 4;
  const int ig = i0 + wave*16 + rl;          // this lane's i (col of S^T)

  __shared__ u16 kt[128][68];                // [j][d]  stride 34 dw -> 2-way
  __shared__ u16 vt[64][132];                // [d][j]
  __shared__ u16 pw[4][16][132];             // per-wave P: [i][j]

  const u16* qrow = qkv + ((long)(b*1024 + ig))*3072 + h*64;
  const bhalf8 qf0 = *(const bhalf8*)(qrow + g*8);
  const bhalf8 qf1 = *(const bhalf8*)(qrow + 32 + g*8);
  const u16* bdbase = bdf + (long)z*ZSTR + 1 + ((long)ig<<10) + 1023 + g*4;

  bhalf8 kreg[2][2], vreg[2][2];
  ushort4 bdreg[3][8];

  auto issueKV = [&](int jt){
    #pragma unroll
    for (int w = 0; w < 2; ++w){
      int r = (tid>>2) + w*64, c = tid&3;
      const u16* sk = qkv + ((long)(b*1024 + jt*128 + r))*3072 + 1024 + h*64 + c*16;
      kreg[w][0] = *(const bhalf8*)(sk);
      kreg[w][1] = *(const bhalf8*)(sk + 8);
      int d = (tid>>3) + w*32, c2 = tid&7;
      const u16* sv = vtb + (long)b*1048576L + ((long)(h*64 + d))*1024 + jt*128 + c2*16;
      vreg[w][0] = *(const bhalf8*)(sv);
      vreg[w][1] = *(const bhalf8*)(sv + 8);
    }
  };

  issueKV(0);
  // prefill bd for tiles 0 and 1 (depth-2 prefetch)
  #pragma unroll
  for (int pt = 0; pt < 2; ++pt){
    const u16* p = bdbase + pt*128;
    #pragma unroll
    for (int jf = 0; jf < 8; ++jf) bdreg[pt][jf] = *(const ushort4*)(p + jf*16);
  }

  f32x4 o[4] = {};
  float m = -INFINITY, l = 0.f;   // l is PER-LANE PARTIAL (reduced in epilogue)

  #pragma unroll
  for (int jt = 0; jt < 8; ++jt){
    // ---- write prefetched K/V regs -> LDS ----
    __syncthreads();
    #pragma unroll
    for (int w = 0; w < 2; ++w){
      int r = (tid>>2) + w*64, c = tid&3;
      *(bhalf8*)&kt[r][c*16]     = kreg[w][0];
      *(bhalf8*)&kt[r][c*16 + 8] = kreg[w][1];
      int d = (tid>>3) + w*32, c2 = tid&7;
      *(bhalf8*)&vt[d][c2*16]     = vreg[w][0];
      *(bhalf8*)&vt[d][c2*16 + 8] = vreg[w][1];
    }
    __syncthreads();

    // ---- issue next tiles' loads; latency hides under this tile's compute ----
    if (jt < 7) issueKV(jt+1);
    if (jt < 6){
      const u16* p = bdbase + (jt+2)*128;
      #pragma unroll
      for (int jf = 0; jf < 8; ++jf) bdreg[(jt+2)%3][jf] = *(const ushort4*)(p + jf*16);
    }

    // ---- S^T = K . Q^T  (+ bd from regs) ----
    f32x4 s[8];
    __builtin_amdgcn_s_setprio(1);
    #pragma unroll
    for (int jf = 0; jf < 8; ++jf){
      bhalf8 a0 = *(const bhalf8*)&kt[jf*16 + rl][g*8];
      bhalf8 a1 = *(const bhalf8*)&kt[jf*16 + rl][32 + g*8];
      f32x4 acc = {};
      acc = __builtin_amdgcn_mfma_f32_16x16x32_bf16(a0, qf0, acc, 0,0,0);
      acc = __builtin_amdgcn_mfma_f32_16x16x32_bf16(a1, qf1, acc, 0,0,0);
      ushort4 bdv = bdreg[jt%3][jf];
      acc[0] += bf2f(bdv.x); acc[1] += bf2f(bdv.y);
      acc[2] += bf2f(bdv.z); acc[3] += bf2f(bdv.w);
      s[jf] = acc;
    }
    __builtin_amdgcn_s_setprio(0);

    // ---- online softmax; T13 defer-max (THR=11.5 in log2 units) ----
    float mt = s[0][0];
    #pragma unroll
    for (int jf = 0; jf < 8; ++jf)
      #pragma unroll
      for (int r2 = 0; r2 < 4; ++r2) mt = fmaxf(mt, s[jf][r2]);
    mt = fmaxf(mt, __shfl_xor(mt, 16));
    mt = fmaxf(mt, __shfl_xor(mt, 32));
    if (__any(mt > m + 11.5f)){
      const float mnew = fmaxf(m, mt);
      const float alpha = exp2f(m - mnew);   // first tile: exp2(-inf)=0
      l *= alpha;                            // row-uniform alpha: partials stay consistent
      #pragma unroll
      for (int df = 0; df < 4; ++df) o[df] *= alpha;
      m = mnew;
    }
    #pragma unroll
    for (int jf = 0; jf < 8; ++jf)
      #pragma unroll
      for (int r2 = 0; r2 < 4; ++r2){
        float p = exp2f(s[jf][r2] - m);
        l += p; s[jf][r2] = p;
      }

    // ---- P -> LDS (bf16, per-wave region; same-wave, no barrier needed) ----
    #pragma unroll
    for (int jf = 0; jf < 8; ++jf){
      uint2 pk;
      pk.x = (unsigned)f2bf(s[jf][0]) | ((unsigned)f2bf(s[jf][1])<<16);
      pk.y = (unsigned)f2bf(s[jf][2]) | ((unsigned)f2bf(s[jf][3])<<16);
      *(uint2*)&pw[wave][rl][jf*16 + g*4] = pk;
    }

    // ---- O^T += V^T . P^T ----
    __builtin_amdgcn_s_setprio(1);
    #pragma unroll
    for (int df = 0; df < 4; ++df)
      #pragma unroll
      for (int kf = 0; kf < 4; ++kf){
        bhalf8 a  = *(const bhalf8*)&vt[df*16 + rl][kf*32 + g*8];
        bhalf8 bf = *(const bhalf8*)&pw[wave][rl][kf*32 + g*8];
        o[df] = __builtin_amdgcn_mfma_f32_16x16x32_bf16(a, bf, o[df], 0,0,0);
      }
    __builtin_amdgcn_s_setprio(0);
  }

  // ---- epilogue: single cross-lane l reduction, then normalize ----
  l += __shfl_xor(l, 16);
  l += __shfl_xor(l, 32);
  const float rlv = 1.0f / l;
  u16* orow = ab + ((long)(b*1024 + ig))*1024 + h*64;
  #pragma unroll
  for (int df = 0; df < 4; ++df){
    ushort4 w4;
    w4.x = f2bf(o[df][0]*rlv); w4.y = f2bf(o[df][1]*rlv);
    w4.z = f2bf(o[df][2]*rlv); w4.w = f2bf(o[df][3]*rlv);
    *(ushort4*)(orow + df*16 + g*4) = w4;
  }
}

// ---------------------------------------------------------------------------
// LayerNorm: out = gamma * (x1+x2 - mean)/sqrt(var+1e-12) + beta, per row(1024)
// ---------------------------------------------------------------------------
__global__ __launch_bounds__(256) void ln_kernel(
    const float* __restrict__ xa, const float* __restrict__ xb2,
    const float* __restrict__ gamma, const float* __restrict__ beta,
    u16* __restrict__ ob, float* __restrict__ of)
{
  const long row = blockIdx.x;
  const int tid = threadIdx.x;
  const float4 a4 = ((const float4*)(xa  + row*1024))[tid];
  const float4 b4 = ((const float4*)(xb2 + row*1024))[tid];
  float v[4] = {a4.x+b4.x, a4.y+b4.y, a4.z+b4.z, a4.w+b4.w};
  float s = v[0]+v[1]+v[2]+v[3];
  __shared__ float red[4];
  s = wredsum(s);
  const int lane = tid&63, w = tid>>6;
  if (!lane) red[w] = s;
  __syncthreads();
  const float mean = (red[0]+red[1]+red[2]+red[3]) * (1.0f/1024.0f);
  float q = 0.f;
  #pragma unroll
  for (int k=0;k<4;k++){ float d = v[k]-mean; q += d*d; }
  __syncthreads();
  q = wredsum(q);
  if (!lane) red[w] = q;
  __syncthreads();
  const float var = (red[0]+red[1]+red[2]+red[3]) * (1.0f/1024.0f);
  const float rstd = rsqrtf(var + 1e-12f);
  const float4 g4 = ((const float4*)gamma)[tid];
  const float4 be4 = ((const float4*)beta)[tid];
  float oo[4];
  oo[0] = g4.x*(v[0]-mean)*rstd + be4.x;
  oo[1] = g4.y*(v[1]-mean)*rstd + be4.y;
  oo[2] = g4.z*(v[2]-mean)*rstd + be4.z;
  oo[3] = g4.w*(v[3]-mean)*rstd + be4.w;
  ushort4 ob4 = { f2bf(oo[0]), f2bf(oo[1]), f2bf(oo[2]), f2bf(oo[3]) };
  *(ushort4*)(ob + row*1024 + tid*4) = ob4;
  float4 of4 = { oo[0], oo[1], oo[2], oo[3] };
  ((float4*)(of + row*1024))[tid] = of4;
}

// ---------------------------------------------------------------------------
// Weight prep: batched f32->bf16 transposes with scale.
// ---------------------------------------------------------------------------
struct TJobs {
  const float* src[16];
  u16* dst[16];
  int R[16], C[16], nb[16];
  float sc[16];
};

__global__ __launch_bounds__(256) void wprep(TJobs J)
{
  const int j = blockIdx.y;
  const int R = J.R[j], C = J.C[j];
  const float scl = J.sc[j];
  const int tR = R>>5, tC = C>>5;
  const int ntiles = tR*tC*J.nb[j];
  const int t = blockIdx.x;
  if (t >= ntiles) return;
  const int b = t/(tR*tC); const int t2 = t%(tR*tC);
  const int tr = t2/tC, tc = t2%tC;
  const float* src = J.src[j] + (long)b*R*C;
  u16* dst = J.dst[j] + (long)b*R*C;
  __shared__ float tl[32][33];
  const int tx = threadIdx.x & 31, ty = threadIdx.x >> 5;
  #pragma unroll
  for (int k=0;k<4;k++){ int r = ty + k*8; tl[r][tx] = src[(long)(tr*32+r)*C + tc*32 + tx]; }
  __syncthreads();
  #pragma unroll
  for (int k=0;k<4;k++){ int r = ty + k*8;
    dst[(long)(tc*32 + r)*R + tr*32 + tx] = f2bf(tl[tx][r]*scl); }
}

// ---------------------------------------------------------------------------
// misc: x,pos -> bf16; bqkv [l][3072] (Q kappa-scaled | K | V) + bqp [l][1024];
// ps pad-slot zero
// ---------------------------------------------------------------------------
__global__ __launch_bounds__(256) void misc_prep(
    const float* __restrict__ x, const float* __restrict__ pos,
    const float* __restrict__ bq, const float* __restrict__ cb, const float* __restrict__ pbv,
    const float* __restrict__ bk, const float* __restrict__ bv,
    u16* __restrict__ xb, u16* __restrict__ posb,
    float* __restrict__ bqkv, float* __restrict__ bqp,
    u16* __restrict__ bd)
{
  const int n1 = 2048*512, n2 = 1024*1024, n3 = 8192;
  int idx = blockIdx.x*256 + threadIdx.x;
  if (idx < n1) { xb[idx] = f2bf(x[idx]); return; }
  idx -= n1;
  if (idx < n2) { posb[idx] = f2bf(pos[idx]); return; }
  idx -= n2;
  if (idx < n3) {
    int l = idx >> 12; int r = idx & 4095;
    if (r < 3072){
      float val;
      if (r < 1024)       val = (bq[l*1024+r] + cb[l*1024+r]) * KAPPA;
      else if (r < 2048)  val = bk[l*1024 + r-1024];
      else                val = bv[l*1024 + r-2048];
      bqkv[l*3072+r] = val;
    } else {
      int n = r - 3072;
      bqp[l*1024+n] = (bq[l*1024+n] + pbv[l*1024+n]) * KAPPA;
    }
    return;
  }
  idx -= n3;
  if (idx < 32*1024) {
    int z = idx >> 10, i = idx & 1023;
    // zero pad slot of each ps row: realizes bd[i][i+1] = 0
    bd[(long)z*ZSTR + 1 + (long)i*1025 + 1024] = 0;
  }
}

// ---------------------------------------------------------------------------
extern "C" void kernel_launch(void* const* d_in, const int* in_sizes, int n_in,
                              void* d_out, int out_size, void* d_ws, size_t ws_size,
                              hipStream_t stream)
{
  (void)in_sizes; (void)n_in; (void)out_size; (void)ws_size;
  const float* x    = (const float*)d_in[0];
  const float* pos  = (const float*)d_in[1];
  const float* Wh1  = (const float*)d_in[2];
  const float* bh1  = (const float*)d_in[3];
  const float* Wh2  = (const float*)d_in[4];
  const float* bh2  = (const float*)d_in[5];
  const float* Wq   = (const float*)d_in[6];
  const float* bq   = (const float*)d_in[7];
  const float* Wk   = (const float*)d_in[8];
  const float* bk   = (const float*)d_in[9];
  const float* Wv   = (const float*)d_in[10];
  const float* bv   = (const float*)d_in[11];
  const float* Wp   = (const float*)d_in[12];
  const float* bp   = (const float*)d_in[13];
  const float* cbias= (const float*)d_in[14];
  const float* pbias= (const float*)d_in[15];
  const float* Wo   = (const float*)d_in[16];
  const float* bo   = (const float*)d_in[17];
  const float* Wf1  = (const float*)d_in[18];
  const float* bf1  = (const float*)d_in[19];
  const float* Wf2  = (const float*)d_in[20];
  const float* bf2  = (const float*)d_in[21];
  const float* lnw  = (const float*)d_in[22];
  const float* lnb  = (const float*)d_in[23];

  const long EL = 1048576L;
  char* ws = (char*)d_ws;
  size_t off = 0;
  auto alloc = [&](size_t bytes)->char* {
    char* p = ws + off; off += (bytes + 255) & ~(size_t)255; return p;
  };
  u16* xb    = (u16*)alloc(2048L*512*2);
  u16* posb  = (u16*)alloc(EL*2);
  u16* Wh1t  = (u16*)alloc(512L*1024*2);
  u16* Wh2t  = (u16*)alloc(EL*2);
  u16* Wqkvt = (u16*)alloc(6*EL*2);     // per layer [3072][1024]: Wq^T|Wk^T|Wv^T
  u16* Wpt   = (u16*)alloc(2*EL*2);
  u16* Wot   = (u16*)alloc(2*EL*2);
  u16* Wf1t  = (u16*)alloc(2*EL*2);
  u16* Wf2t  = (u16*)alloc(2*EL*2);
  float* bqkv= (float*)alloc(2*3072*4);
  float* bqp = (float*)alloc(2*1024*4);
  u16* t1    = (u16*)alloc(2048L*1024*2);
  u16* hb    = (u16*)alloc(2048L*1024*2);
  float* hf  = (float*)alloc(2048L*1024*4);
  u16* qkvb  = (u16*)alloc(2048L*3072*2);  // [2048][3072] Q|K|(V unused)
  u16* qp    = (u16*)alloc(2048L*1024*2);
  u16* vtb   = (u16*)alloc(2048L*1024*2);
  u16* pb    = (u16*)alloc(2*EL*2);        // both layers' pos projections
  u16* bd    = (u16*)alloc(32L*ZSTR*2);    // stride-1025 ps (pre-shifted bd view)
  u16* ab    = (u16*)alloc(2048L*1024*2);
  float* aof = (float*)alloc(2048L*1024*4);
  u16* h1b   = (u16*)alloc(2048L*1024*2);
  float* h1f = (float*)alloc(2048L*1024*4);
  u16* f1b   = (u16*)alloc(2048L*1024*2);
  float* f2f = (float*)alloc(2048L*1024*4);

  // ---- setup ----
  misc_prep<<<dim3((2048*512 + 1024*1024 + 8192 + 32*1024 + 255)/256),
              dim3(256), 0, stream>>>(
      x, pos, bq, cbias, pbias, bk, bv, xb, posb, bqkv, bqp, bd);

  TJobs J; int ji = 0;
  auto addjob = [&](const float* s, u16* d, int R, int C, int nb, float sc){
    J.src[ji]=s; J.dst[ji]=d; J.R[ji]=R; J.C[ji]=C; J.nb[ji]=nb; J.sc[ji]=sc; ji++;
  };
  addjob(Wh1, Wh1t, 512, 1024, 1, 1.f);
  addjob(Wh2, Wh2t, 1024, 1024, 1, 1.f);
  for (int l=0;l<2;l++) addjob(Wq + l*EL, Wqkvt + l*3*EL,        1024, 64, 16, KAPPA);
  for (int l=0;l<2;l++) addjob(Wk + l*EL, Wqkvt + l*3*EL + EL,   1024, 64, 16, 1.f);
  for (int l=0;l<2;l++) addjob(Wv + l*EL, Wqkvt + l*3*EL + 2*EL, 1024, 64, 16, 1.f);
  for (int l=0;l<2;l++) addjob(Wp + l*EL, Wpt + l*EL, 1024, 64, 16, 1.f);
  for (int l=0;l<2;l++) addjob(Wo + l*EL, Wot + l*EL, 1024, 1024, 1, 1.f);
  for (int l=0;l<2;l++) addjob(Wf1 + l*EL, Wf1t + l*EL, 1024, 1024, 1, 1.f);
  for (int l=0;l<2;l++) addjob(Wf2 + l*EL, Wf2t + l*EL, 1024, 1024, 1, 1.f);
  wprep<<<dim3(1024, 16), dim3(256), 0, stream>>>(J);

  // ---- to_hidden MLP (64x64 tiles: TLP overlap) ----
  launch_gemm<64,64,7>(stream, 2048,1024,512,  xb,512,0,0,  Wh1t,512,0,0,
                 t1,nullptr,nullptr,1024,0,0,  bh1,nullptr, 0, 1,1);
  launch_gemm<64,64,21>(stream, 2048,1024,1024, t1,1024,0,0, Wh2t,1024,0,0,
                 hb,hf,nullptr,1024,0,0,  bh2,nullptr, 0, 1,1);

  // ---- both layers' pos projections in one batched launch (z = layer) ----
  launch_gemm<64,64,5>(stream, 1024,1024,1024, posb,1024, 0,0, Wpt,1024, EL,0,
                 pb,nullptr,nullptr,1024, EL,0,  bp,nullptr, 1024, 2,1);

  for (int l=0; l<2; l++){
    const u16 *Wqkvt_l = Wqkvt + l*3*EL, *Wot_l = Wot + l*EL,
              *Wf1t_l = Wf1t + l*EL, *Wf2t_l = Wf2t + l*EL;
    // fused QKV: N=3072, 128x64 tile (reuse-optimal; 64x64 doubled B traffic)
    launch_gemm<128,64,64>(stream, 2048,3072,1024, hb,1024,0,0, Wqkvt_l,1024,0,0,
                    qkvb,qp,vtb,3072,0,0,  bqkv + l*3072, bqp + l*1024, 0, 1,1);
    // ps = qp@p^T, stored stride-1025 (+1 offset) => pre-shifted bd view
    launch_gemm<128,64,4>(stream, 1024,1024,64,  qp,1024, EL,64,  pb + l*EL,1024, 0,64,
                    bd+1,nullptr,nullptr,1025, 16L*ZSTR, ZSTR,  nullptr,nullptr, 0, 32,16);
    // fused attention (v11, frozen)
    flash_attn<<<dim3(16,32), dim3(256), 0, stream>>>(qkvb, vtb, bd, ab);
    // output proj
    launch_gemm<64,64,1>(stream, 2048,1024,1024, ab,1024,0,0, Wot_l,1024,0,0,
                    aof,nullptr,nullptr,1024,0,0,  bo + l*1024, nullptr, 0, 1,1);
    // h1 = LN(a + h)
    ln_kernel<<<dim3(2048), dim3(256), 0, stream>>>(aof, hf, lnw + l*1024, lnb + l*1024, h1b, h1f);
    // FFN
    launch_gemm<64,64,7>(stream, 2048,1024,1024, h1b,1024,0,0, Wf1t_l,1024,0,0,
                    f1b,nullptr,nullptr,1024,0,0,  bf1 + l*1024, nullptr, 0, 1,1);
    launch_gemm<64,64,1>(stream, 2048,1024,1024, f1b,1024,0,0, Wf2t_l,1024,0,0,
                    f2f,nullptr,nullptr,1024,0,0,  bf2 + l*1024, nullptr, 0, 1,1);
    // h = LN(h1 + f)
    float* outf = (l==1) ? (float*)d_out : hf;
    ln_kernel<<<dim3(2048), dim3(256), 0, stream>>>(f2f, h1f, lnw + l*1024, lnb + l*1024, hb, outf);
  }
}